// Round 1
// baseline (119806.506 us; speedup 1.0000x reference)
//
#include <hip/hip_runtime.h>
#include <math.h>

#define CC 1024
#define LL 2048
#define NWG 256
#define NT 256

// ws layout (float words):
// [0]       : unsigned barrier counter (memset to 0 each launch)
// [64 ..)   : logits[2048]
// [2112 ..) : av[1024]
// [3136 ..) : h0n[1024]
// [4160 ..) : h1n[1024]
#define WS_LOGITS 64
#define WS_AV     (WS_LOGITS + LL)
#define WS_H0N    (WS_AV + CC)
#define WS_H1N    (WS_H0N + CC)

__device__ __forceinline__ float aload(const float* p) {
  return __hip_atomic_load(p, __ATOMIC_RELAXED, __HIP_MEMORY_SCOPE_AGENT);
}
__device__ __forceinline__ void astore(float* p, float v) {
  __hip_atomic_store(p, v, __ATOMIC_RELAXED, __HIP_MEMORY_SCOPE_AGENT);
}
__device__ __forceinline__ float sigm(float x) { return 1.0f / (1.0f + __expf(-x)); }
__device__ __forceinline__ float tanh_(float x) { return 2.0f / (1.0f + __expf(-2.0f * x)) - 1.0f; }

__device__ __forceinline__ float wred(float v) {
#pragma unroll
  for (int off = 32; off; off >>= 1) v += __shfl_xor(v, off, 64);
  return v;
}

__device__ __forceinline__ float dotrow(const float4* wr, const float4* hc) {
  float p = 0.f;
#pragma unroll
  for (int k = 0; k < 4; ++k) {
    p = fmaf(wr[k].x, hc[k].x, p);
    p = fmaf(wr[k].y, hc[k].y, p);
    p = fmaf(wr[k].z, hc[k].z, p);
    p = fmaf(wr[k].w, hc[k].w, p);
  }
  return p;
}

__device__ __forceinline__ void gbar(unsigned* ctr, unsigned target) {
  __threadfence();
  __syncthreads();
  if (threadIdx.x == 0) {
    __hip_atomic_fetch_add(ctr, 1u, __ATOMIC_RELEASE, __HIP_MEMORY_SCOPE_AGENT);
    while (__hip_atomic_load(ctr, __ATOMIC_ACQUIRE, __HIP_MEMORY_SCOPE_AGENT) < target) {
    }
  }
  __syncthreads();
}

__global__ __launch_bounds__(NT, 1) void decoder_kernel(
    const float* __restrict__ x, const float* __restrict__ attn_w,
    const float* __restrict__ w_ih0, const float* __restrict__ w_hh0,
    const float* __restrict__ b_ih0, const float* __restrict__ b_hh0,
    const float* __restrict__ w_ih1, const float* __restrict__ w_hh1,
    const float* __restrict__ b_ih1, const float* __restrict__ b_hh1,
    float* __restrict__ out, float* __restrict__ ws) {
  const int g = blockIdx.x;
  const int tid = threadIdx.x;
  const int lane = tid & 63;
  const int w = tid >> 6;

  unsigned* ctr = (unsigned*)ws;
  float* logits = ws + WS_LOGITS;
  float* avg = ws + WS_AV;
  float* h0n_g = ws + WS_H0N;
  float* h1n_g = ws + WS_H1N;

  __shared__ __align__(16) float h0s[CC];
  __shared__ __align__(16) float h1s[CC];
  __shared__ float stA0[16], stA1[16], stB[16];
  __shared__ float cgi0[16], cbh0[16], cbh1[16], cbi1[16];
  __shared__ float red[NT];

  unsigned nbar = 0;

  // ---------- P0: logits[t] = dot(w2, x[t]) for this WG's 8 timesteps ----------
  {
    const float* w2 = attn_w + CC;  // second half applies to x
#pragma unroll
    for (int s = 0; s < 2; ++s) {
      int t = 8 * g + 2 * w + s;
      const float* xr = x + (size_t)t * CC;
      float p = 0.f;
#pragma unroll
      for (int k = 0; k < 4; ++k) {
        float4 xa = *(const float4*)(xr + 256 * k + 4 * lane);
        float4 wa = *(const float4*)(w2 + 256 * k + 4 * lane);
        p = fmaf(xa.x, wa.x, p);
        p = fmaf(xa.y, wa.y, p);
        p = fmaf(xa.z, wa.z, p);
        p = fmaf(xa.w, wa.w, p);
      }
      p = wred(p);
      if (lane == 0) astore(&logits[t], p);
    }
  }
  gbar(ctr, (++nbar) * NWG);

  // ---------- P1: softmax over L (replicated m,Z), av columns [4g,4g+4) ----------
  {
    float myl[8];
#pragma unroll
    for (int s = 0; s < 8; ++s) myl[s] = aload(&logits[tid + 256 * s]);
    float lm = myl[0];
#pragma unroll
    for (int s = 1; s < 8; ++s) lm = fmaxf(lm, myl[s]);
    red[tid] = lm;
    __syncthreads();
    for (int st = 128; st; st >>= 1) {
      if (tid < st) red[tid] = fmaxf(red[tid], red[tid + st]);
      __syncthreads();
    }
    float m = red[0];
    __syncthreads();
    float myw[8];
    float ls = 0.f;
#pragma unroll
    for (int s = 0; s < 8; ++s) {
      myw[s] = __expf(myl[s] - m);
      ls += myw[s];
    }
    red[tid] = ls;
    __syncthreads();
    for (int st = 128; st; st >>= 1) {
      if (tid < st) red[tid] += red[tid + st];
      __syncthreads();
    }
    float invZ = 1.0f / red[0];
    __syncthreads();
    float acc[4] = {0.f, 0.f, 0.f, 0.f};
#pragma unroll
    for (int s = 0; s < 8; ++s) {
      int t = tid + 256 * s;
      float4 xa = *(const float4*)(x + (size_t)t * CC + 4 * g);
      acc[0] = fmaf(myw[s], xa.x, acc[0]);
      acc[1] = fmaf(myw[s], xa.y, acc[1]);
      acc[2] = fmaf(myw[s], xa.z, acc[2]);
      acc[3] = fmaf(myw[s], xa.w, acc[3]);
    }
    for (int i = 0; i < 4; ++i) {
      red[tid] = acc[i];
      __syncthreads();
      for (int st = 128; st; st >>= 1) {
        if (tid < st) red[tid] += red[tid + st];
        __syncthreads();
      }
      if (tid == 0) astore(&avg[4 * g + i], red[0] * invZ);
      __syncthreads();
    }
  }
  gbar(ctr, (++nbar) * NWG);

  // ---------- P2: gi0 = W_ih0 . av + b_ih0 (only this WG's 12 rows); biases; weights->VGPR ----------
#pragma unroll
  for (int i = 0; i < 4; ++i) h0s[4 * tid + i] = aload(&avg[4 * tid + i]);
  __syncthreads();
  {
    float4 hc[4];
#pragma unroll
    for (int k = 0; k < 4; ++k) hc[k] = *(const float4*)&h0s[256 * k + 4 * lane];
#pragma unroll
    for (int jj = 0; jj < 3; ++jj) {
      int j = 3 * w + jj;
      int gate = j >> 2, ei = j & 3;
      int row = gate * CC + 4 * g + ei;
      const float* wr = w_ih0 + (size_t)row * CC;
      float4 wv[4];
#pragma unroll
      for (int k = 0; k < 4; ++k) wv[k] = *(const float4*)(wr + 256 * k + 4 * lane);
      float p = wred(dotrow(wv, hc));
      if (lane == 0) cgi0[j] = p + b_ih0[row];
    }
  }
  if (tid < 12) {
    int j = tid;
    int gate = j >> 2, ei = j & 3;
    int row = gate * CC + 4 * g + ei;
    cbh0[j] = b_hh0[row];
    cbh1[j] = b_hh1[row];
    cbi1[j] = b_ih1[row];
  }
  __syncthreads();
#pragma unroll
  for (int i = 0; i < 4; ++i) {
    h0s[4 * tid + i] = 0.f;
    h1s[4 * tid + i] = 0.f;
  }
  // load this lane's slices of the 9 rows it owns into registers
  float4 wA0[3][4], wA1[3][4], wB[3][4];
#pragma unroll
  for (int jj = 0; jj < 3; ++jj) {
    int j = 3 * w + jj;
    int gate = j >> 2, ei = j & 3;
    size_t row = (size_t)(gate * CC + 4 * g + ei) * CC;
#pragma unroll
    for (int k = 0; k < 4; ++k) {
      wA0[jj][k] = *(const float4*)(w_hh0 + row + 256 * k + 4 * lane);
      wA1[jj][k] = *(const float4*)(w_hh1 + row + 256 * k + 4 * lane);
      wB[jj][k] = *(const float4*)(w_ih1 + row + 256 * k + 4 * lane);
    }
  }
  __syncthreads();

  // ---------- main recurrence ----------
  float h0new = 0.f;
  for (int t = 0; t < LL; ++t) {
    // (a) refresh h1 replica from previous step's h1n
    if (t > 0) {
#pragma unroll
      for (int i = 0; i < 4; ++i) h1s[4 * tid + i] = aload(&h1n_g[4 * tid + i]);
    }
    __syncthreads();
    // (b) phase A: rows of W_hh0 (x h0) and W_hh1 (x h1)
    {
      float4 hc0[4], hc1[4];
#pragma unroll
      for (int k = 0; k < 4; ++k) {
        hc0[k] = *(const float4*)&h0s[256 * k + 4 * lane];
        hc1[k] = *(const float4*)&h1s[256 * k + 4 * lane];
      }
#pragma unroll
      for (int jj = 0; jj < 3; ++jj) {
        float pa = wred(dotrow(wA0[jj], hc0));
        float pb = wred(dotrow(wA1[jj], hc1));
        if (lane == 0) {
          stA0[3 * w + jj] = pa;
          stA1[3 * w + jj] = pb;
        }
      }
    }
    __syncthreads();
    // (c) elementwise layer-0 update for this WG's 4 elements
    if (tid < 4) {
      int e = 4 * g + tid;
      float hr = stA0[tid] + cbh0[tid];
      float hz = stA0[4 + tid] + cbh0[4 + tid];
      float hn = stA0[8 + tid] + cbh0[8 + tid];
      float r = sigm(cgi0[tid] + hr);
      float z = sigm(cgi0[4 + tid] + hz);
      float n = tanh_(cgi0[8 + tid] + r * hn);
      h0new = (1.f - z) * n + z * h0s[e];
      astore(&h0n_g[e], h0new);
    }
    gbar(ctr, (++nbar) * NWG);
    // (d) refresh h0 replica
#pragma unroll
    for (int i = 0; i < 4; ++i) h0s[4 * tid + i] = aload(&h0n_g[4 * tid + i]);
    __syncthreads();
    // (e) phase B: rows of W_ih1 (x h0n)
    {
      float4 hc[4];
#pragma unroll
      for (int k = 0; k < 4; ++k) hc[k] = *(const float4*)&h0s[256 * k + 4 * lane];
#pragma unroll
      for (int jj = 0; jj < 3; ++jj) {
        float pc = wred(dotrow(wB[jj], hc));
        if (lane == 0) stB[3 * w + jj] = pc;
      }
    }
    __syncthreads();
    // (f) elementwise layer-1 update, write out[t]
    if (tid < 4) {
      int e = 4 * g + tid;
      float ir = stB[tid] + cbi1[tid];
      float iz = stB[4 + tid] + cbi1[4 + tid];
      float inn = stB[8 + tid] + cbi1[8 + tid];
      float hr = stA1[tid] + cbh1[tid];
      float hz = stA1[4 + tid] + cbh1[4 + tid];
      float hn = stA1[8 + tid] + cbh1[8 + tid];
      float r = sigm(ir + hr);
      float z = sigm(iz + hz);
      float n = tanh_(inn + r * hn);
      float h1new = (1.f - z) * n + z * h1s[e];
      astore(&h1n_g[e], h1new);
      out[(size_t)t * CC + e] = h1new;
      if (t == LL - 1) {
        out[(size_t)LL * CC + e] = h0new;       // final h0
        out[(size_t)LL * CC + CC + e] = h1new;  // final h1
      }
    }
    gbar(ctr, (++nbar) * NWG);
  }
}

extern "C" void kernel_launch(void* const* d_in, const int* in_sizes, int n_in,
                              void* d_out, int out_size, void* d_ws, size_t ws_size,
                              hipStream_t stream) {
  const float* x = (const float*)d_in[0];
  const float* attn_w = (const float*)d_in[1];
  const float* w_ih0 = (const float*)d_in[3];
  const float* w_hh0 = (const float*)d_in[4];
  const float* b_ih0 = (const float*)d_in[5];
  const float* b_hh0 = (const float*)d_in[6];
  const float* w_ih1 = (const float*)d_in[7];
  const float* w_hh1 = (const float*)d_in[8];
  const float* b_ih1 = (const float*)d_in[9];
  const float* b_hh1 = (const float*)d_in[10];
  float* out = (float*)d_out;
  float* ws = (float*)d_ws;

  // zero the barrier counter region every call (deterministic)
  hipMemsetAsync(d_ws, 0, 256, stream);

  void* args[] = {&x,      &attn_w, &w_ih0,  &w_hh0, &b_ih0, &b_hh0,
                  &w_ih1,  &w_hh1,  &b_ih1,  &b_hh1, &out,   &ws};
  hipLaunchCooperativeKernel((void*)decoder_kernel, dim3(NWG), dim3(NT), args, 0,
                             stream);
}

// Round 2
// 31361.734 us; speedup vs baseline: 3.8201x; 3.8201x over previous
//
#include <hip/hip_runtime.h>
#include <math.h>

#define CC 1024
#define LL 2048
#define NWG 256
#define NT 256

// ws layout (float/unsigned words):
// [i*32], i<256 : per-WG arrival epoch (own 128B line each)   [memset 0]
// [8192]        : release epoch flag (own line)               [memset 0]
// [8256 ..)     : logits[2048]
// [.. ]         : av[1024], h0n[1024], h1n[1024]
#define WS_FLAGS  0
#define WS_REL    8192
#define WS_LOGITS 8256
#define WS_AV     (WS_LOGITS + LL)
#define WS_H0N    (WS_AV + CC)
#define WS_H1N    (WS_H0N + CC)

__device__ __forceinline__ float aload(const float* p) {
  return __hip_atomic_load(p, __ATOMIC_RELAXED, __HIP_MEMORY_SCOPE_AGENT);
}
__device__ __forceinline__ void astore(float* p, float v) {
  __hip_atomic_store(p, v, __ATOMIC_RELAXED, __HIP_MEMORY_SCOPE_AGENT);
}
__device__ __forceinline__ float sigm(float x) { return 1.0f / (1.0f + __expf(-x)); }
__device__ __forceinline__ float tanh_(float x) { return 2.0f / (1.0f + __expf(-2.0f * x)) - 1.0f; }

__device__ __forceinline__ float wred(float v) {
#pragma unroll
  for (int off = 32; off; off >>= 1) v += __shfl_xor(v, off, 64);
  return v;
}

__device__ __forceinline__ float dotrow(const float4* wr, const float4* hc) {
  float p = 0.f;
#pragma unroll
  for (int k = 0; k < 4; ++k) {
    p = fmaf(wr[k].x, hc[k].x, p);
    p = fmaf(wr[k].y, hc[k].y, p);
    p = fmaf(wr[k].z, hc[k].z, p);
    p = fmaf(wr[k].w, hc[k].w, p);
  }
  return p;
}

// Arrival-slot barrier: no RMW anywhere.
//  - WG g>0: thread0 release-stores epoch to its own line, then spins on the
//    release flag (relaxed; one final acquire load for visibility).
//  - WG 0: threads 1..255 each poll one arrival slot (parallel gather, relaxed
//    spin + final acquire), then thread0 release-stores the release flag.
__device__ __forceinline__ void gbar(unsigned* ws_u, unsigned epoch) {
  __syncthreads();  // drains vmem (compiler emits waitcnt) -> prior astores done
  if (blockIdx.x == 0) {
    const int i = threadIdx.x;
    if (i > 0 && i < NWG) {
      unsigned* slot = ws_u + WS_FLAGS + i * 32;
      while (__hip_atomic_load(slot, __ATOMIC_RELAXED, __HIP_MEMORY_SCOPE_AGENT) < epoch) {
      }
      (void)__hip_atomic_load(slot, __ATOMIC_ACQUIRE, __HIP_MEMORY_SCOPE_AGENT);
    }
    __syncthreads();
    if (i == 0) {
      __hip_atomic_store(ws_u + WS_REL, epoch, __ATOMIC_RELEASE, __HIP_MEMORY_SCOPE_AGENT);
    }
    __syncthreads();
  } else {
    if (threadIdx.x == 0) {
      __hip_atomic_store(ws_u + WS_FLAGS + blockIdx.x * 32, epoch, __ATOMIC_RELEASE,
                         __HIP_MEMORY_SCOPE_AGENT);
      unsigned* rel = ws_u + WS_REL;
      while (__hip_atomic_load(rel, __ATOMIC_RELAXED, __HIP_MEMORY_SCOPE_AGENT) < epoch) {
      }
      (void)__hip_atomic_load(rel, __ATOMIC_ACQUIRE, __HIP_MEMORY_SCOPE_AGENT);
    }
    __syncthreads();
  }
}

__global__ __launch_bounds__(NT, 1) void decoder_kernel(
    const float* __restrict__ x, const float* __restrict__ attn_w,
    const float* __restrict__ w_ih0, const float* __restrict__ w_hh0,
    const float* __restrict__ b_ih0, const float* __restrict__ b_hh0,
    const float* __restrict__ w_ih1, const float* __restrict__ w_hh1,
    const float* __restrict__ b_ih1, const float* __restrict__ b_hh1,
    float* __restrict__ out, float* __restrict__ ws) {
  const int g = blockIdx.x;
  const int tid = threadIdx.x;
  const int lane = tid & 63;
  const int w = tid >> 6;

  unsigned* ws_u = (unsigned*)ws;
  float* logits = ws + WS_LOGITS;
  float* avg = ws + WS_AV;
  float* h0n_g = ws + WS_H0N;
  float* h1n_g = ws + WS_H1N;

  __shared__ __align__(16) float h0s[CC];
  __shared__ __align__(16) float h1s[CC];
  __shared__ float stA0[16], stA1[16], stB[16];
  __shared__ float cgi0[16], cbh0[16], cbh1[16], cbi1[16];
  __shared__ float red[NT];

  unsigned nbar = 0;

  // ---------- P0: logits[t] = dot(w2, x[t]) for this WG's 8 timesteps ----------
  {
    const float* w2 = attn_w + CC;  // second half applies to x
#pragma unroll
    for (int s = 0; s < 2; ++s) {
      int t = 8 * g + 2 * w + s;
      const float* xr = x + (size_t)t * CC;
      float p = 0.f;
#pragma unroll
      for (int k = 0; k < 4; ++k) {
        float4 xa = *(const float4*)(xr + 256 * k + 4 * lane);
        float4 wa = *(const float4*)(w2 + 256 * k + 4 * lane);
        p = fmaf(xa.x, wa.x, p);
        p = fmaf(xa.y, wa.y, p);
        p = fmaf(xa.z, wa.z, p);
        p = fmaf(xa.w, wa.w, p);
      }
      p = wred(p);
      if (lane == 0) astore(&logits[t], p);
    }
  }
  gbar(ws_u, ++nbar);

  // ---------- P1: softmax over L (replicated m,Z), av columns [4g,4g+4) ----------
  {
    float myl[8];
#pragma unroll
    for (int s = 0; s < 8; ++s) myl[s] = aload(&logits[tid + 256 * s]);
    float lm = myl[0];
#pragma unroll
    for (int s = 1; s < 8; ++s) lm = fmaxf(lm, myl[s]);
    red[tid] = lm;
    __syncthreads();
    for (int st = 128; st; st >>= 1) {
      if (tid < st) red[tid] = fmaxf(red[tid], red[tid + st]);
      __syncthreads();
    }
    float m = red[0];
    __syncthreads();
    float myw[8];
    float ls = 0.f;
#pragma unroll
    for (int s = 0; s < 8; ++s) {
      myw[s] = __expf(myl[s] - m);
      ls += myw[s];
    }
    red[tid] = ls;
    __syncthreads();
    for (int st = 128; st; st >>= 1) {
      if (tid < st) red[tid] += red[tid + st];
      __syncthreads();
    }
    float invZ = 1.0f / red[0];
    __syncthreads();
    float acc[4] = {0.f, 0.f, 0.f, 0.f};
#pragma unroll
    for (int s = 0; s < 8; ++s) {
      int t = tid + 256 * s;
      float4 xa = *(const float4*)(x + (size_t)t * CC + 4 * g);
      acc[0] = fmaf(myw[s], xa.x, acc[0]);
      acc[1] = fmaf(myw[s], xa.y, acc[1]);
      acc[2] = fmaf(myw[s], xa.z, acc[2]);
      acc[3] = fmaf(myw[s], xa.w, acc[3]);
    }
    for (int i = 0; i < 4; ++i) {
      red[tid] = acc[i];
      __syncthreads();
      for (int st = 128; st; st >>= 1) {
        if (tid < st) red[tid] += red[tid + st];
        __syncthreads();
      }
      if (tid == 0) astore(&avg[4 * g + i], red[0] * invZ);
      __syncthreads();
    }
  }
  gbar(ws_u, ++nbar);

  // ---------- P2: gi0 = W_ih0 . av + b_ih0 (only this WG's 12 rows); biases; weights->VGPR ----------
#pragma unroll
  for (int i = 0; i < 4; ++i) h0s[4 * tid + i] = aload(&avg[4 * tid + i]);
  __syncthreads();
  {
    float4 hc[4];
#pragma unroll
    for (int k = 0; k < 4; ++k) hc[k] = *(const float4*)&h0s[256 * k + 4 * lane];
#pragma unroll
    for (int jj = 0; jj < 3; ++jj) {
      int j = 3 * w + jj;
      int gate = j >> 2, ei = j & 3;
      int row = gate * CC + 4 * g + ei;
      const float* wr = w_ih0 + (size_t)row * CC;
      float4 wv[4];
#pragma unroll
      for (int k = 0; k < 4; ++k) wv[k] = *(const float4*)(wr + 256 * k + 4 * lane);
      float p = wred(dotrow(wv, hc));
      if (lane == 0) cgi0[j] = p + b_ih0[row];
    }
  }
  if (tid < 12) {
    int j = tid;
    int gate = j >> 2, ei = j & 3;
    int row = gate * CC + 4 * g + ei;
    cbh0[j] = b_hh0[row];
    cbh1[j] = b_hh1[row];
    cbi1[j] = b_ih1[row];
  }
  __syncthreads();
#pragma unroll
  for (int i = 0; i < 4; ++i) {
    h0s[4 * tid + i] = 0.f;
    h1s[4 * tid + i] = 0.f;
  }
  // load this lane's slices of the 9 rows it owns into registers
  float4 wA0[3][4], wA1[3][4], wB[3][4];
#pragma unroll
  for (int jj = 0; jj < 3; ++jj) {
    int j = 3 * w + jj;
    int gate = j >> 2, ei = j & 3;
    size_t row = (size_t)(gate * CC + 4 * g + ei) * CC;
#pragma unroll
    for (int k = 0; k < 4; ++k) {
      wA0[jj][k] = *(const float4*)(w_hh0 + row + 256 * k + 4 * lane);
      wA1[jj][k] = *(const float4*)(w_hh1 + row + 256 * k + 4 * lane);
      wB[jj][k] = *(const float4*)(w_ih1 + row + 256 * k + 4 * lane);
    }
  }
  __syncthreads();

  // ---------- main recurrence ----------
  float h0new = 0.f;
  for (int t = 0; t < LL; ++t) {
    // (a) refresh h1 replica from previous step's h1n
    if (t > 0) {
#pragma unroll
      for (int i = 0; i < 4; ++i) h1s[4 * tid + i] = aload(&h1n_g[4 * tid + i]);
    }
    __syncthreads();
    // (b) phase A: rows of W_hh0 (x h0) and W_hh1 (x h1)
    {
      float4 hc0[4], hc1[4];
#pragma unroll
      for (int k = 0; k < 4; ++k) {
        hc0[k] = *(const float4*)&h0s[256 * k + 4 * lane];
        hc1[k] = *(const float4*)&h1s[256 * k + 4 * lane];
      }
#pragma unroll
      for (int jj = 0; jj < 3; ++jj) {
        float pa = wred(dotrow(wA0[jj], hc0));
        float pb = wred(dotrow(wA1[jj], hc1));
        if (lane == 0) {
          stA0[3 * w + jj] = pa;
          stA1[3 * w + jj] = pb;
        }
      }
    }
    __syncthreads();
    // (c) elementwise layer-0 update for this WG's 4 elements
    if (tid < 4) {
      int e = 4 * g + tid;
      float hr = stA0[tid] + cbh0[tid];
      float hz = stA0[4 + tid] + cbh0[4 + tid];
      float hn = stA0[8 + tid] + cbh0[8 + tid];
      float r = sigm(cgi0[tid] + hr);
      float z = sigm(cgi0[4 + tid] + hz);
      float n = tanh_(cgi0[8 + tid] + r * hn);
      h0new = (1.f - z) * n + z * h0s[e];
      astore(&h0n_g[e], h0new);
    }
    gbar(ws_u, ++nbar);
    // (d) refresh h0 replica
#pragma unroll
    for (int i = 0; i < 4; ++i) h0s[4 * tid + i] = aload(&h0n_g[4 * tid + i]);
    __syncthreads();
    // (e) phase B: rows of W_ih1 (x h0n)
    {
      float4 hc[4];
#pragma unroll
      for (int k = 0; k < 4; ++k) hc[k] = *(const float4*)&h0s[256 * k + 4 * lane];
#pragma unroll
      for (int jj = 0; jj < 3; ++jj) {
        float pc = wred(dotrow(wB[jj], hc));
        if (lane == 0) stB[3 * w + jj] = pc;
      }
    }
    __syncthreads();
    // (f) elementwise layer-1 update, write out[t]
    if (tid < 4) {
      int e = 4 * g + tid;
      float ir = stB[tid] + cbi1[tid];
      float iz = stB[4 + tid] + cbi1[4 + tid];
      float inn = stB[8 + tid] + cbi1[8 + tid];
      float hr = stA1[tid] + cbh1[tid];
      float hz = stA1[4 + tid] + cbh1[4 + tid];
      float hn = stA1[8 + tid] + cbh1[8 + tid];
      float r = sigm(ir + hr);
      float z = sigm(iz + hz);
      float n = tanh_(inn + r * hn);
      float h1new = (1.f - z) * n + z * h1s[e];
      astore(&h1n_g[e], h1new);
      out[(size_t)t * CC + e] = h1new;
      if (t == LL - 1) {
        out[(size_t)LL * CC + e] = h0new;       // final h0
        out[(size_t)LL * CC + CC + e] = h1new;  // final h1
      }
    }
    gbar(ws_u, ++nbar);
  }
}

extern "C" void kernel_launch(void* const* d_in, const int* in_sizes, int n_in,
                              void* d_out, int out_size, void* d_ws, size_t ws_size,
                              hipStream_t stream) {
  const float* x = (const float*)d_in[0];
  const float* attn_w = (const float*)d_in[1];
  const float* w_ih0 = (const float*)d_in[3];
  const float* w_hh0 = (const float*)d_in[4];
  const float* b_ih0 = (const float*)d_in[5];
  const float* b_hh0 = (const float*)d_in[6];
  const float* w_ih1 = (const float*)d_in[7];
  const float* w_hh1 = (const float*)d_in[8];
  const float* b_ih1 = (const float*)d_in[9];
  const float* b_hh1 = (const float*)d_in[10];
  float* out = (float*)d_out;
  float* ws = (float*)d_ws;

  // zero the barrier flag region (arrival slots + release flag) every call
  hipMemsetAsync(d_ws, 0, (WS_LOGITS) * sizeof(float), stream);

  void* args[] = {&x,      &attn_w, &w_ih0,  &w_hh0, &b_ih0, &b_hh0,
                  &w_ih1,  &w_hh1,  &b_ih1,  &b_hh1, &out,   &ws};
  hipLaunchCooperativeKernel((void*)decoder_kernel, dim3(NWG), dim3(NT), args, 0,
                             stream);
}